// Round 1
// baseline (186.901 us; speedup 1.0000x reference)
//
#include <hip/hip_runtime.h>

#define CNT   2048
#define NSTEP 2047      // CNT-1 integration steps
#define TPB   256
#define CHUNK 8         // steps per thread (256*8 = 2048 >= 2047)

struct Q { float w, x, y, z; };

__device__ inline Q qmul(const Q a, const Q b) {
    Q o;
    o.w = a.w*b.w - a.x*b.x - a.y*b.y - a.z*b.z;
    o.x = a.w*b.x + a.x*b.w + a.y*b.z - a.z*b.y;
    o.y = a.w*b.y - a.x*b.z + a.y*b.w + a.z*b.x;
    o.z = a.w*b.z + a.x*b.y - a.y*b.x + a.z*b.w;
    return o;
}

__global__ __launch_bounds__(TPB) void quat_scan_kernel(
    const float* __restrict__ ts,    // (B, CNT)
    const float* __restrict__ gyro,  // (B, CNT, 3)
    const float* __restrict__ sq,    // (B, 4)
    const float* __restrict__ W1, const float* __restrict__ b1, const float* __restrict__ a1p,
    const float* __restrict__ W2, const float* __restrict__ b2, const float* __restrict__ a2p,
    float* __restrict__ out)         // (B, 4)
{
    __shared__ float s_g[CNT * 3];   // 24 KB
    __shared__ float s_t[CNT];       // 8 KB
    __shared__ Q     s_q[TPB];       // 4 KB

    const int b   = blockIdx.x;
    const int tid = threadIdx.x;

    // ---- stage gyro row (6144 floats) + ts row (2048 floats), float4-coalesced
    const float4* g4  = (const float4*)(gyro + (size_t)b * (CNT * 3));
    float4*       sg4 = (float4*)s_g;
    #pragma unroll
    for (int k = 0; k < 6; ++k) sg4[tid + k * TPB] = g4[tid + k * TPB];

    const float4* t4  = (const float4*)(ts + (size_t)b * CNT);
    float4*       st4 = (float4*)s_t;
    #pragma unroll
    for (int k = 0; k < 2; ++k) st4[tid + k * TPB] = t4[tid + k * TPB];

    // ---- small params into registers (broadcast loads, L2-cached)
    float w1[9], w2[9], bb1[3], bb2[3];
    #pragma unroll
    for (int i = 0; i < 9; ++i) { w1[i] = W1[i]; w2[i] = W2[i]; }
    #pragma unroll
    for (int i = 0; i < 3; ++i) { bb1[i] = b1[i]; bb2[i] = b2[i]; }
    const float a1 = a1p[0], a2 = a2p[0];

    __syncthreads();

    // g(t) = prelu(W2 @ prelu(W1 @ v + b1, a1) + b2, a2) + v   (einsum 'oc': row-major W[o*3+c])
    auto gf = [&](int t, float& gx, float& gy, float& gz) {
        const float vx = s_g[3*t + 0], vy = s_g[3*t + 1], vz = s_g[3*t + 2];
        float h0 = w1[0]*vx + w1[1]*vy + w1[2]*vz + bb1[0];
        float h1 = w1[3]*vx + w1[4]*vy + w1[5]*vz + bb1[1];
        float h2 = w1[6]*vx + w1[7]*vy + w1[8]*vz + bb1[2];
        h0 = h0 >= 0.0f ? h0 : a1 * h0;
        h1 = h1 >= 0.0f ? h1 : a1 * h1;
        h2 = h2 >= 0.0f ? h2 : a1 * h2;
        float u0 = w2[0]*h0 + w2[1]*h1 + w2[2]*h2 + bb2[0];
        float u1 = w2[3]*h0 + w2[4]*h1 + w2[5]*h2 + bb2[1];
        float u2 = w2[6]*h0 + w2[7]*h1 + w2[8]*h2 + bb2[2];
        u0 = u0 >= 0.0f ? u0 : a2 * u0;
        u1 = u1 >= 0.0f ? u1 : a2 * u1;
        u2 = u2 >= 0.0f ? u2 : a2 * u2;
        gx = u0 + vx; gy = u1 + vy; gz = u2 + vz;
    };

    // ---- ordered chunk product of this thread's dq's
    const int t0   = tid * CHUNK;
    int       tend = t0 + CHUNK;
    if (tend > NSTEP) tend = NSTEP;   // only tid==255 trims (7 steps)

    Q q = {1.0f, 0.0f, 0.0f, 0.0f};
    float g0x, g0y, g0z;
    gf(t0, g0x, g0y, g0z);
    for (int t = t0; t < tend; ++t) {
        float g1x, g1y, g1z;
        gf(t + 1, g1x, g1y, g1z);
        const float dt = s_t[t + 1] - s_t[t];
        const float s  = 0.25f * dt;                 // gm*dt*0.5 = (g0+g1)*dt*0.25
        const Q dq = {1.0f, (g0x + g1x) * s, (g0y + g1y) * s, (g0z + g1z) * s};
        q = qmul(q, dq);
        g0x = g1x; g0y = g1y; g0z = g1z;
    }

    // normalize chunk product (positive rescale: direction-preserving, keeps tree bounded)
    {
        const float n2  = q.w*q.w + q.x*q.x + q.y*q.y + q.z*q.z;
        const float inv = 1.0f / sqrtf(n2);          // n2 >= 1 always (dq.w == 1)
        q.w *= inv; q.x *= inv; q.y *= inv; q.z *= inv;
    }

    s_q[tid] = q;
    __syncthreads();

    // ---- ordered in-place tree reduction: s_q[tid] = s_q[tid] (*) s_q[tid+stride]
    #pragma unroll
    for (int stride = 1; stride < TPB; stride <<= 1) {
        if ((tid & (2 * stride - 1)) == 0) {
            s_q[tid] = qmul(s_q[tid], s_q[tid + stride]);
        }
        __syncthreads();
    }

    // ---- epilogue: apply start quat, final normalize with EPS clamp
    if (tid == 0) {
        const float4 s0 = ((const float4*)(sq + (size_t)b * 4))[0];
        const Q q0 = {s0.x, s0.y, s0.z, s0.w};
        Q qf = qmul(q0, s_q[0]);
        const float n  = sqrtf(qf.w*qf.w + qf.x*qf.x + qf.y*qf.y + qf.z*qf.z);
        const float dn = fmaxf(n, 1e-12f);
        const float inv = 1.0f / dn;
        float4 o;
        o.x = qf.w * inv; o.y = qf.x * inv; o.z = qf.y * inv; o.w = qf.z * inv;
        ((float4*)(out + (size_t)b * 4))[0] = o;
    }
}

extern "C" void kernel_launch(void* const* d_in, const int* in_sizes, int n_in,
                              void* d_out, int out_size, void* d_ws, size_t ws_size,
                              hipStream_t stream) {
    const float* ts   = (const float*)d_in[0];  // timestampns_set (B, CNT)
    const float* gyro = (const float*)d_in[1];  // gyro_set (B, CNT, 3)
    const float* sq   = (const float*)d_in[2];  // start_quat (B, 4)
    const float* W1   = (const float*)d_in[3];
    const float* b1   = (const float*)d_in[4];
    const float* a1   = (const float*)d_in[5];
    const float* W2   = (const float*)d_in[6];
    const float* b2   = (const float*)d_in[7];
    const float* a2   = (const float*)d_in[8];
    float* out = (float*)d_out;

    const int B = in_sizes[0] / CNT;  // 4096

    quat_scan_kernel<<<B, TPB, 0, stream>>>(ts, gyro, sq, W1, b1, a1, W2, b2, a2, out);
}

// Round 2
// 185.873 us; speedup vs baseline: 1.0055x; 1.0055x over previous
//
#include <hip/hip_runtime.h>

#define CNT   2048
#define NSTEP 2047      // CNT-1 integration steps
#define TPB   256
#define CHUNK 8         // steps per thread (256*8 = 2048 >= 2047)
#define NWAVE (TPB / 64)

struct Q { float w, x, y, z; };

__device__ inline Q qmul(const Q a, const Q b) {
    Q o;
    o.w = a.w*b.w - a.x*b.x - a.y*b.y - a.z*b.z;
    o.x = a.w*b.x + a.x*b.w + a.y*b.z - a.z*b.y;
    o.y = a.w*b.y - a.x*b.z + a.y*b.w + a.z*b.x;
    o.z = a.w*b.z + a.x*b.y - a.y*b.x + a.z*b.w;
    return o;
}

// qmul specialized for b.w == 1: o = a ⊗ (1, bx, by, bz)
__device__ inline Q qmul1(const Q a, const float bx, const float by, const float bz) {
    Q o;
    o.w = a.w - (a.x*bx + a.y*by + a.z*bz);
    o.x = a.x + (a.w*bx + a.y*bz - a.z*by);
    o.y = a.y + (a.w*by - a.x*bz + a.z*bx);
    o.z = a.z + (a.w*bz + a.x*by - a.y*bx);
    return o;
}

__global__ __launch_bounds__(TPB) void quat_scan_kernel(
    const float* __restrict__ ts,    // (B, CNT)
    const float* __restrict__ gyro,  // (B, CNT, 3)
    const float* __restrict__ sq,    // (B, 4)
    const float* __restrict__ W1, const float* __restrict__ b1, const float* __restrict__ a1p,
    const float* __restrict__ W2, const float* __restrict__ b2, const float* __restrict__ a2p,
    float* __restrict__ out)         // (B, 4)
{
    __shared__ Q s_q[NWAVE];         // 64 B — the only LDS

    const int b    = blockIdx.x;
    const int tid  = threadIdx.x;
    const int t0   = tid * CHUNK;
    const bool last = (tid == TPB - 1);

    // ---- per-thread contiguous segment straight into registers
    // gyro samples t0 .. t0+8  (27 floats). Byte offset = 96*tid -> 16B aligned.
    float rg[28];
    {
        const float4* gp = (const float4*)(gyro + (size_t)b * (CNT * 3) + (size_t)t0 * 3);
        #pragma unroll
        for (int k = 0; k < 6; ++k) ((float4*)rg)[k] = gp[k];   // samples t0..t0+7, always in-range
        if (!last) {
            ((float4*)rg)[6] = gp[6];                            // floats 24..27 (sample t0+8)
        } else {
            ((float4*)rg)[6] = make_float4(0.f, 0.f, 0.f, 0.f);  // pad: finite, unused via dt=0
        }
    }
    // ts samples t0 .. t0+8 (9 floats). Byte offset = 32*tid -> 16B aligned.
    float rt[9];
    {
        const float4* tp = (const float4*)(ts + (size_t)b * CNT + t0);
        #pragma unroll
        for (int k = 0; k < 2; ++k) ((float4*)&rt[0])[k] = tp[k];  // t0..t0+7
        rt[8] = last ? rt[7] : ts[(size_t)b * CNT + t0 + 8];       // dt=0 for the pad step
    }

    // ---- small params (broadcast, L2-cached)
    float w1[9], w2[9], bb1[3], bb2[3];
    #pragma unroll
    for (int i = 0; i < 9; ++i) { w1[i] = W1[i]; w2[i] = W2[i]; }
    #pragma unroll
    for (int i = 0; i < 3; ++i) { bb1[i] = b1[i]; bb2[i] = b2[i]; }
    const float a1 = a1p[0], a2 = a2p[0];

    // g(j) = prelu(W2 @ prelu(W1 @ v + b1, a1) + b2, a2) + v  (einsum 'oc': W[o*3+c])
    auto gf = [&](int j, float& gx, float& gy, float& gz) {
        const float vx = rg[3*j + 0], vy = rg[3*j + 1], vz = rg[3*j + 2];
        float h0 = w1[0]*vx + w1[1]*vy + w1[2]*vz + bb1[0];
        float h1 = w1[3]*vx + w1[4]*vy + w1[5]*vz + bb1[1];
        float h2 = w1[6]*vx + w1[7]*vy + w1[8]*vz + bb1[2];
        h0 = h0 >= 0.0f ? h0 : a1 * h0;
        h1 = h1 >= 0.0f ? h1 : a1 * h1;
        h2 = h2 >= 0.0f ? h2 : a1 * h2;
        float u0 = w2[0]*h0 + w2[1]*h1 + w2[2]*h2 + bb2[0];
        float u1 = w2[3]*h0 + w2[4]*h1 + w2[5]*h2 + bb2[1];
        float u2 = w2[6]*h0 + w2[7]*h1 + w2[8]*h2 + bb2[2];
        u0 = u0 >= 0.0f ? u0 : a2 * u0;
        u1 = u1 >= 0.0f ? u1 : a2 * u1;
        u2 = u2 >= 0.0f ? u2 : a2 * u2;
        gx = u0 + vx; gy = u1 + vy; gz = u2 + vz;
    };

    // ---- ordered chunk product, fully unrolled, branch-free (pad step is identity)
    Q q = {1.0f, 0.0f, 0.0f, 0.0f};
    float g0x, g0y, g0z;
    gf(0, g0x, g0y, g0z);
    #pragma unroll
    for (int j = 0; j < CHUNK; ++j) {
        float g1x, g1y, g1z;
        gf(j + 1, g1x, g1y, g1z);
        const float s = 0.25f * (rt[j + 1] - rt[j]);   // gm*dt*0.5 = (g0+g1)*dt*0.25
        q = qmul1(q, (g0x + g1x) * s, (g0y + g1y) * s, (g0z + g1z) * s);
        g0x = g1x; g0y = g1y; g0z = g1z;
    }

    // normalize chunk product (positive rescale, keeps reduction bounded; n2 >= 1)
    {
        const float n2  = q.w*q.w + q.x*q.x + q.y*q.y + q.z*q.z;
        const float inv = 1.0f / sqrtf(n2);
        q.w *= inv; q.x *= inv; q.y *= inv; q.z *= inv;
    }

    // ---- ordered wave-level shuffle reduction (lane 0 gets P_0 ⊗ ... ⊗ P_63)
    #pragma unroll
    for (int sft = 1; sft < 64; sft <<= 1) {
        Q o;
        o.w = __shfl_down(q.w, sft);
        o.x = __shfl_down(q.x, sft);
        o.y = __shfl_down(q.y, sft);
        o.z = __shfl_down(q.z, sft);
        q = qmul(q, o);
    }

    const int lane = tid & 63;
    const int wid  = tid >> 6;
    if (lane == 0) s_q[wid] = q;
    __syncthreads();

    // ---- epilogue: combine wave products in order, apply start quat, normalize
    if (tid == 0) {
        Q acc = s_q[0];
        #pragma unroll
        for (int w = 1; w < NWAVE; ++w) acc = qmul(acc, s_q[w]);

        const float4 s0 = ((const float4*)(sq + (size_t)b * 4))[0];
        const Q q0 = {s0.x, s0.y, s0.z, s0.w};
        Q qf = qmul(q0, acc);
        const float n   = sqrtf(qf.w*qf.w + qf.x*qf.x + qf.y*qf.y + qf.z*qf.z);
        const float inv = 1.0f / fmaxf(n, 1e-12f);
        float4 o;
        o.x = qf.w * inv; o.y = qf.x * inv; o.z = qf.y * inv; o.w = qf.z * inv;
        ((float4*)(out + (size_t)b * 4))[0] = o;
    }
}

extern "C" void kernel_launch(void* const* d_in, const int* in_sizes, int n_in,
                              void* d_out, int out_size, void* d_ws, size_t ws_size,
                              hipStream_t stream) {
    const float* ts   = (const float*)d_in[0];  // timestampns_set (B, CNT)
    const float* gyro = (const float*)d_in[1];  // gyro_set (B, CNT, 3)
    const float* sq   = (const float*)d_in[2];  // start_quat (B, 4)
    const float* W1   = (const float*)d_in[3];
    const float* b1   = (const float*)d_in[4];
    const float* a1   = (const float*)d_in[5];
    const float* W2   = (const float*)d_in[6];
    const float* b2   = (const float*)d_in[7];
    const float* a2   = (const float*)d_in[8];
    float* out = (float*)d_out;

    const int B = in_sizes[0] / CNT;  // 4096

    quat_scan_kernel<<<B, TPB, 0, stream>>>(ts, gyro, sq, W1, b1, a1, W2, b2, a2, out);
}

// Round 3
// 184.334 us; speedup vs baseline: 1.0139x; 1.0083x over previous
//
#include <hip/hip_runtime.h>

#define CNT   2048
#define NSTEP 2047      // CNT-1 integration steps
#define TPB   256
#define CHUNK 8         // steps per thread (256*8 = 2048 >= 2047)
#define NWAVE (TPB / 64)

// padded LDS index: insert one float of pad every 8 floats.
// read lane-stride 24 floats -> padded stride 27 (gcd(27,32)=1) -> conflict-free
#define PAD(f) ((f) + ((f) >> 3))
#define GPAD_SZ (CNT * 3 + ((CNT * 3) >> 3))   // 6912 floats = 27648 B

struct Q { float w, x, y, z; };

__device__ inline Q qmul(const Q a, const Q b) {
    Q o;
    o.w = a.w*b.w - a.x*b.x - a.y*b.y - a.z*b.z;
    o.x = a.w*b.x + a.x*b.w + a.y*b.z - a.z*b.y;
    o.y = a.w*b.y - a.x*b.z + a.y*b.w + a.z*b.x;
    o.z = a.w*b.z + a.x*b.y - a.y*b.x + a.z*b.w;
    return o;
}

// qmul specialized for b.w == 1: o = a ⊗ (1, bx, by, bz)
__device__ inline Q qmul1(const Q a, const float bx, const float by, const float bz) {
    Q o;
    o.w = a.w - (a.x*bx + a.y*by + a.z*bz);
    o.x = a.x + (a.w*bx + a.y*bz - a.z*by);
    o.y = a.y + (a.w*by - a.x*bz + a.z*bx);
    o.z = a.z + (a.w*bz + a.x*by - a.y*bx);
    return o;
}

__global__ __launch_bounds__(TPB) void quat_scan_kernel(
    const float* __restrict__ ts,    // (B, CNT)
    const float* __restrict__ gyro,  // (B, CNT, 3)
    const float* __restrict__ sq,    // (B, 4)
    const float* __restrict__ W1, const float* __restrict__ b1, const float* __restrict__ a1p,
    const float* __restrict__ W2, const float* __restrict__ b2, const float* __restrict__ a2p,
    float* __restrict__ out)         // (B, 4)
{
    __shared__ float s_g[GPAD_SZ];   // padded gyro row, 27.6 KB
    __shared__ Q     s_q[NWAVE];

    const int b    = blockIdx.x;
    const int tid  = threadIdx.x;
    const int t0   = tid * CHUNK;
    const bool last = (tid == TPB - 1);

    // ---- coalesced gyro staging: float4 global loads -> padded scalar LDS writes
    {
        const float4* g4 = (const float4*)(gyro + (size_t)b * (CNT * 3));
        #pragma unroll
        for (int k = 0; k < 6; ++k) {
            const int   fi = 4 * (tid + k * TPB);   // first float index of this float4
            const float4 v = g4[tid + k * TPB];
            s_g[PAD(fi + 0)] = v.x;
            s_g[PAD(fi + 1)] = v.y;
            s_g[PAD(fi + 2)] = v.z;
            s_g[PAD(fi + 3)] = v.w;
        }
    }

    // ---- ts segment into registers (t0 .. t0+8); lane stride 32B, 2x-amplified only
    float rt[9];
    {
        const float4* tp = (const float4*)(ts + (size_t)b * CNT + t0);
        #pragma unroll
        for (int k = 0; k < 2; ++k) ((float4*)&rt[0])[k] = tp[k];     // t0..t0+7
        rt[8] = last ? rt[7] : ts[(size_t)b * CNT + t0 + 8];          // dt=0 pad step
    }

    // ---- small params (broadcast, L2-cached)
    float w1[9], w2[9], bb1[3], bb2[3];
    #pragma unroll
    for (int i = 0; i < 9; ++i) { w1[i] = W1[i]; w2[i] = W2[i]; }
    #pragma unroll
    for (int i = 0; i < 3; ++i) { bb1[i] = b1[i]; bb2[i] = b2[i]; }
    const float a1 = a1p[0], a2 = a2p[0];

    __syncthreads();

    // g(t) = prelu(W2 @ prelu(W1 @ v + b1, a1) + b2, a2) + v  (einsum 'oc': W[o*3+c])
    auto gf = [&](int t, float& gx, float& gy, float& gz) {
        const int f = 3 * t;
        const float vx = s_g[PAD(f + 0)];
        const float vy = s_g[PAD(f + 1)];
        const float vz = s_g[PAD(f + 2)];
        float h0 = w1[0]*vx + w1[1]*vy + w1[2]*vz + bb1[0];
        float h1 = w1[3]*vx + w1[4]*vy + w1[5]*vz + bb1[1];
        float h2 = w1[6]*vx + w1[7]*vy + w1[8]*vz + bb1[2];
        h0 = h0 >= 0.0f ? h0 : a1 * h0;
        h1 = h1 >= 0.0f ? h1 : a1 * h1;
        h2 = h2 >= 0.0f ? h2 : a1 * h2;
        float u0 = w2[0]*h0 + w2[1]*h1 + w2[2]*h2 + bb2[0];
        float u1 = w2[3]*h0 + w2[4]*h1 + w2[5]*h2 + bb2[1];
        float u2 = w2[6]*h0 + w2[7]*h1 + w2[8]*h2 + bb2[2];
        u0 = u0 >= 0.0f ? u0 : a2 * u0;
        u1 = u1 >= 0.0f ? u1 : a2 * u1;
        u2 = u2 >= 0.0f ? u2 : a2 * u2;
        gx = u0 + vx; gy = u1 + vy; gz = u2 + vz;
    };

    // ---- ordered chunk product, fully unrolled, branch-free (pad step has dt=0)
    Q q = {1.0f, 0.0f, 0.0f, 0.0f};
    float g0x, g0y, g0z;
    gf(t0, g0x, g0y, g0z);
    #pragma unroll
    for (int j = 0; j < CHUNK; ++j) {
        const int t1 = (t0 + j + 1 < CNT) ? (t0 + j + 1) : (CNT - 1);  // clamp (tid=255 pad)
        float g1x, g1y, g1z;
        gf(t1, g1x, g1y, g1z);
        const float s = 0.25f * (rt[j + 1] - rt[j]);   // gm*dt*0.5 = (g0+g1)*dt*0.25
        q = qmul1(q, (g0x + g1x) * s, (g0y + g1y) * s, (g0z + g1z) * s);
        g0x = g1x; g0y = g1y; g0z = g1z;
    }

    // normalize chunk product (positive rescale, keeps reduction bounded; n2 >= 1)
    {
        const float n2  = q.w*q.w + q.x*q.x + q.y*q.y + q.z*q.z;
        const float inv = 1.0f / sqrtf(n2);
        q.w *= inv; q.x *= inv; q.y *= inv; q.z *= inv;
    }

    // ---- ordered wave-level shuffle reduction (lane 0 gets P_0 ⊗ ... ⊗ P_63)
    #pragma unroll
    for (int sft = 1; sft < 64; sft <<= 1) {
        Q o;
        o.w = __shfl_down(q.w, sft);
        o.x = __shfl_down(q.x, sft);
        o.y = __shfl_down(q.y, sft);
        o.z = __shfl_down(q.z, sft);
        q = qmul(q, o);
    }

    const int lane = tid & 63;
    const int wid  = tid >> 6;
    if (lane == 0) s_q[wid] = q;
    __syncthreads();

    // ---- epilogue: combine wave products in order, apply start quat, normalize
    if (tid == 0) {
        Q acc = s_q[0];
        #pragma unroll
        for (int w = 1; w < NWAVE; ++w) acc = qmul(acc, s_q[w]);

        const float4 s0 = ((const float4*)(sq + (size_t)b * 4))[0];
        const Q q0 = {s0.x, s0.y, s0.z, s0.w};
        Q qf = qmul(q0, acc);
        const float n   = sqrtf(qf.w*qf.w + qf.x*qf.x + qf.y*qf.y + qf.z*qf.z);
        const float inv = 1.0f / fmaxf(n, 1e-12f);
        float4 o;
        o.x = qf.w * inv; o.y = qf.x * inv; o.z = qf.y * inv; o.w = qf.z * inv;
        ((float4*)(out + (size_t)b * 4))[0] = o;
    }
}

extern "C" void kernel_launch(void* const* d_in, const int* in_sizes, int n_in,
                              void* d_out, int out_size, void* d_ws, size_t ws_size,
                              hipStream_t stream) {
    const float* ts   = (const float*)d_in[0];  // timestampns_set (B, CNT)
    const float* gyro = (const float*)d_in[1];  // gyro_set (B, CNT, 3)
    const float* sq   = (const float*)d_in[2];  // start_quat (B, 4)
    const float* W1   = (const float*)d_in[3];
    const float* b1   = (const float*)d_in[4];
    const float* a1   = (const float*)d_in[5];
    const float* W2   = (const float*)d_in[6];
    const float* b2   = (const float*)d_in[7];
    const float* a2   = (const float*)d_in[8];
    float* out = (float*)d_out;

    const int B = in_sizes[0] / CNT;  // 4096

    quat_scan_kernel<<<B, TPB, 0, stream>>>(ts, gyro, sq, W1, b1, a1, W2, b2, a2, out);
}